// Round 11
// baseline (254.014 us; speedup 1.0000x reference)
//
#include <hip/hip_runtime.h>

// MHA B=2, T=2048, D=1024, H=16, nd=64. fp32 I/O, bf16 MFMA internally.
// softmax over QUERY axis (dim=-2), causal, fixed-max (|z|<~3):
//   l[tk] = sum_{tq>=tk} exp(z); out[tq] = sum_{tk<=tq} exp(z)/l[tk] * v[tk]
// Scale 1/8 * log2(e) folded into Q projection -> single v_exp_f32 per score.
// V stored pre-transposed [B, D, T] (plain; dsw-staged into LDS, 3-bit ldv4).
// Round 16 = BISECT of r10's absmax fail (r10 bundled attn_stats-batch2 AND
// attn_out-8wave; inspection can't arbitrate).  This round: attn_out is
// r9-EXACT (the 46.8us passing 4-wave batch-2 version, verbatim); attn_stats
// keeps r10's batch-2 Q staging.  Single mechanism under test: stats-batch2.
// If FAIL -> stats-batch2 condemned, r17 = pure r9.  If PASS -> 8-wave
// condemned; drain-amortization continues via other levers at 4 waves.
// GEMMs, cvt: r9-exact.

#define Dd 1024
#define Tt 2048
#define Bb 2
#define Hh 16
#define NDh 64
#define Mm (Bb * Tt)
#define LOG2E 1.44269504f

using u16 = unsigned short;
using u32 = unsigned int;
typedef __attribute__((ext_vector_type(8))) short bf16x8;
typedef __attribute__((ext_vector_type(4))) short bf16x4;
typedef __attribute__((ext_vector_type(4))) float f32x4;

__device__ __forceinline__ u16 f2bf(float f) {
  return (u16)((__float_as_uint(f) + 0x8000u) >> 16);
}
__device__ __forceinline__ float exp2_hw(float x) {  // single v_exp_f32
  float r; asm("v_exp_f32 %0, %1" : "=v"(r) : "v"(x)); return r;
}
__device__ __forceinline__ u32 cvtpk(float lo, float hi) {  // 2xf32 -> bf16 pair
  u32 r; asm("v_cvt_pk_bf16_f32 %0, %1, %2" : "=v"(r) : "v"(lo), "v"(hi));
  return r;
}
// async global->LDS, 16B per lane; LDS dest = base + lane*16 (wave-uniform base)
__device__ __forceinline__ void ldsdma16(const u16* g, u16* l) {
  __builtin_amdgcn_global_load_lds(
      (const __attribute__((address_space(1))) u32*)g,
      (__attribute__((address_space(3))) u32*)l, 16, 0, 0);
}
#define MFMA(a, b, c) __builtin_amdgcn_mfma_f32_16x16x32_bf16((a), (b), (c), 0, 0, 0)
__device__ __forceinline__ f32x4 mfma16(bf16x4 a, bf16x4 b, f32x4 c) {
#if __has_builtin(__builtin_amdgcn_mfma_f32_16x16x16bf16_1k)
  return __builtin_amdgcn_mfma_f32_16x16x16bf16_1k(a, b, c, 0, 0, 0);
#else
  f32x4 d;
  asm("v_mfma_f32_16x16x16_bf16 %0, %1, %2, %3"
      : "=v"(d) : "v"(a), "v"(b), "0"(c));
  return d;
#endif
}
// frag load from swizzled 64-elem-row tile (16B-granule XOR, K/Q tiles)
__device__ __forceinline__ bf16x8 ldfrag(const u16* lds, int row, int kgrp) {
  return *(const bf16x8*)(lds + row * 64 + (((kgrp) ^ (row & 7)) * 8));
}
// 4-elem (8B) load from dsw-staged tile; e0 = element offset, multiple of 4
__device__ __forceinline__ bf16x4 ldv4(const u16* lds, int row, int e0) {
  return *(const bf16x4*)(lds + row * 64 + (((e0 >> 3) ^ (row & 7)) * 8) + (e0 & 7));
}

// ---------------------------------------------------------------------------
// Convert weights (4x Dd*Dd) AND q/k/v (3x Mm*Dd) fp32 -> bf16;
// zero d_out and lsum. 16 segments of 2^18 float4 each; grid 16384x256.
// ---------------------------------------------------------------------------
__global__ __launch_bounds__(256) void cvt_all(
    const float* __restrict__ w0, const float* __restrict__ w1,
    const float* __restrict__ w2, const float* __restrict__ w3,
    const float* __restrict__ xq, const float* __restrict__ xk,
    const float* __restrict__ xv,
    u16* __restrict__ Wb, u16* __restrict__ Qb, u16* __restrict__ Kb,
    u16* __restrict__ Vb, float* __restrict__ outz, float* __restrict__ lsumz)
{
  const int vid = blockIdx.x * 256 + threadIdx.x;     // 4M vec4 units
  const int seg = vid >> 18;                          // 16 segs of 1M floats
  const size_t off = (size_t)(vid & 0x3FFFF) * 4;
  const float* s;
  u16* d;
  if (seg < 4) {                                      // weights
    s = seg == 0 ? w0 : seg == 1 ? w1 : seg == 2 ? w2 : w3;
    d = Wb + (size_t)seg * Dd * Dd;
  } else {                                            // q/k/v (4 segs each)
    const int xi = (seg - 4) >> 2;
    const size_t xo = (size_t)((seg - 4) & 3) << 20;  // sub-offset in floats
    s = (xi == 0 ? xq : xi == 1 ? xk : xv) + xo;
    d = (xi == 0 ? Qb : xi == 1 ? Kb : Vb) + xo;
  }
  float4 f = *(const float4*)(s + off);
  ushort4 o;
  o.x = f2bf(f.x); o.y = f2bf(f.y); o.z = f2bf(f.z); o.w = f2bf(f.w);
  *(ushort4*)(d + off) = o;
  if (vid < Mm * Dd / 4)                              // zero out (4M floats)
    *(float4*)(outz + (size_t)vid * 4) = make_float4(0.f, 0.f, 0.f, 0.f);
  if (vid < Bb * Hh * Tt / 4)
    *(float4*)(lsumz + (size_t)vid * 4) = make_float4(0.f, 0.f, 0.f, 0.f);
}

// ---------------------------------------------------------------------------
// GEMM body: Y[m,n] = (sum_k X[m,k]*W[n,k] + bias[n]) * oscale.  All bf16 in.
// BM=64, BN=128, BK=64, 256 thr / 4 waves (2Mx2N), wave tile 32x64 = 2x4 frags.
// Both A and B staged via global_load_lds width-16; single-buffered m97 body.
// omode 0: bf16 Y[m*Dd+n]*oscale; 1: bf16 transposed (Y[b,n,t]); 2: f32 atomic.
// Split-K: kc/knum (omode 2 only; bias added by kc==0).
// ---------------------------------------------------------------------------
__device__ __forceinline__ void gemm_body(
    const u16* __restrict__ X, const u16* __restrict__ WB,
    const float* __restrict__ bias, void* Yv, float oscale, int omode,
    int kc, int knum, u16* As, u16* Bs)
{
  const int t = threadIdx.x, lane = t & 63, w = t >> 6;
  const int col = lane & 15, quad = lane >> 4;
  const int m0 = blockIdx.x * 64, n0 = blockIdx.y * 128;
  const int wm = (w >> 1) * 32, wn = (w & 1) * 64;
  const int drr = lane >> 3, dsw = ((lane & 7) ^ drr) * 8;  // swizzled src col
  const int kbeg = (Dd / knum) * kc, kend = kbeg + Dd / knum;

  f32x4 acc[2][4] = {};

  for (int k0 = kbeg; k0 < kend; k0 += 64) {
    __syncthreads();  // previous iteration's frag readers done
#pragma unroll
    for (int i = 0; i < 2; i++) {
      const int rr = w * 16 + i * 8;
      ldsdma16(X + (size_t)(m0 + rr + drr) * Dd + k0 + dsw, As + rr * 64);
    }
#pragma unroll
    for (int i = 0; i < 4; i++) {
      const int rr = w * 32 + i * 8;
      ldsdma16(WB + (size_t)(n0 + rr + drr) * Dd + k0 + dsw, Bs + rr * 64);
    }
    __syncthreads();  // drains dma (vmcnt)
#pragma unroll
    for (int s = 0; s < 2; s++) {
      bf16x8 a[2], b[4];
#pragma unroll
      for (int i = 0; i < 2; i++)
        a[i] = ldfrag(As, wm + i * 16 + col, s * 4 + quad);
#pragma unroll
      for (int j = 0; j < 4; j++)
        b[j] = ldfrag(Bs, wn + j * 16 + col, s * 4 + quad);
#pragma unroll
      for (int i = 0; i < 2; i++)
#pragma unroll
        for (int j = 0; j < 4; j++)
          acc[i][j] = MFMA(a[i], b[j], acc[i][j]);
    }
  }

#pragma unroll
  for (int jt = 0; jt < 4; jt++) {
    const int n = n0 + wn + jt * 16 + col;
    const float bn = (omode == 2 && kc != 0) ? 0.f : bias[n];
    if (omode == 1) {
#pragma unroll
      for (int i = 0; i < 2; i++) {
        const int mg = m0 + wm + i * 16 + quad * 4;
        const int bb = mg >> 11, tl = mg & 2047;
        ushort4 o;
        o.x = f2bf(acc[i][jt][0] + bn);
        o.y = f2bf(acc[i][jt][1] + bn);
        o.z = f2bf(acc[i][jt][2] + bn);
        o.w = f2bf(acc[i][jt][3] + bn);
        *(ushort4*)((u16*)Yv + (size_t)bb * Dd * Tt + (size_t)n * Tt + tl) = o;
      }
    } else if (omode == 0) {
      u16* Y = (u16*)Yv;
#pragma unroll
      for (int i = 0; i < 2; i++)
#pragma unroll
        for (int r = 0; r < 4; r++) {
          const int m = m0 + wm + i * 16 + quad * 4 + r;
          Y[(size_t)m * Dd + n] = f2bf((acc[i][jt][r] + bn) * oscale);
        }
    } else {
      float* Y = (float*)Yv;
#pragma unroll
      for (int i = 0; i < 2; i++)
#pragma unroll
        for (int r = 0; r < 4; r++) {
          const int m = m0 + wm + i * 16 + quad * 4 + r;
          atomicAdd(&Y[(size_t)m * Dd + n], acc[i][jt][r] + bn);
        }
    }
  }
}

// Fused Q/K/V projection: blockIdx.z selects input/weight/output.
__global__ __launch_bounds__(256) void proj_qkv(
    const u16* __restrict__ Qb, const u16* __restrict__ Kb,
    const u16* __restrict__ Vb, const u16* __restrict__ Wb,
    const float* __restrict__ bq, const float* __restrict__ bk,
    const float* __restrict__ bv,
    u16* __restrict__ Qp, u16* __restrict__ Kp, u16* __restrict__ VtG)
{
  __shared__ u16 As[64 * 64];
  __shared__ u16 Bs[128 * 64];
  const int z = blockIdx.z;
  const u16* X = z == 0 ? Qb : z == 1 ? Kb : Vb;
  const u16* W = Wb + (size_t)z * Dd * Dd;
  const float* bias = z == 0 ? bq : z == 1 ? bk : bv;
  void* Y = z == 0 ? (void*)Qp : z == 1 ? (void*)Kp : (void*)VtG;
  // Q scale = 1/8 * log2(e): attn kernels then use raw exp2 (1 v_exp_f32)
  gemm_body(X, W, bias, Y, z == 0 ? 0.125f * LOG2E : 1.0f, z == 2 ? 1 : 0,
            0, 1, As, Bs);
}

__global__ __launch_bounds__(256) void gemm_final(
    const u16* __restrict__ Ctx, const u16* __restrict__ Wcb,
    const float* __restrict__ bc, float* __restrict__ out)
{
  __shared__ u16 As[64 * 64];
  __shared__ u16 Bs[128 * 64];
  gemm_body(Ctx, Wcb, bc, out, 1.0f, 2, blockIdx.z, 2, As, Bs);
}

// ---------------------------------------------------------------------------
// Pass A: lsum[tk] += partial sum_{tq>=tk} exp(z).
// Grid (bh, 16 tk-tiles of 128, 4 tq-chunks). Wave: 32 tk, K-frags in regs.
// BATCH-2 Q staging: stage Q tiles d and d+4 per drain (literal buffer
// indices), compute both.  Masked only on very first tile (c<2, i0==0).
// ---------------------------------------------------------------------------
__global__ __launch_bounds__(256) void attn_stats(
    const u16* __restrict__ Qp, const u16* __restrict__ Kp,
    float* __restrict__ lsum)
{
  __shared__ u16 Ks[128 * 64];
  __shared__ u16 Qs[2][64 * 64];
  const int t = threadIdx.x, lane = t & 63, w = t >> 6;
  const int col = lane & 15, quad = lane >> 4;
  const int bh = blockIdx.x, b = bh >> 4, h = bh & 15;
  const int j = blockIdx.y, tk0 = j * 128, c = blockIdx.z;
  const u16* Kbase = Kp + (size_t)b * Tt * Dd + h * NDh;
  const u16* Qbase = Qp + (size_t)b * Tt * Dd + h * NDh;
  const int drr = lane >> 3, dsw = ((lane & 7) ^ drr) * 8;

#pragma unroll
  for (int i = 0; i < 4; i++) {
    const int rr = w * 32 + i * 8;
    ldsdma16(Kbase + (size_t)(tk0 + rr + drr) * Dd + dsw, Ks + rr * 64);
  }
  __syncthreads();
  bf16x8 ka[2][2];
#pragma unroll
  for (int s2 = 0; s2 < 2; s2++) {
    const int row = w * 32 + s2 * 16 + col;
    ka[s2][0] = ldfrag(Ks, row, quad);
    ka[s2][1] = ldfrag(Ks, row, 4 + quad);
  }

  float l[2][4] = {};

  auto computeS = [&](const u16* Qc, int tq0, bool masked) {
#pragma unroll
    for (int jt = 0; jt < 4; jt++) {
      bf16x8 qb0 = ldfrag(Qc, jt * 16 + col, quad);
      bf16x8 qb1 = ldfrag(Qc, jt * 16 + col, 4 + quad);
      const int tq = tq0 + jt * 16 + col;
#pragma unroll
      for (int s2 = 0; s2 < 2; s2++) {
        f32x4 z = {};
        z = MFMA(ka[s2][0], qb0, z);
        z = MFMA(ka[s2][1], qb1, z);
#pragma unroll
        for (int r = 0; r < 4; r++) {
          float e = exp2_hw(z[r]);
          if (masked) {
            const int tk = tk0 + w * 32 + s2 * 16 + quad * 4 + r;
            e = (tq >= tk) ? e : 0.f;
          }
          l[s2][r] += e;
        }
      }
    }
  };

  const int d0 = 2 * j + c;
  for (int d = d0, i0 = 0; d < Tt / 64; d += 8, i0++) {
    const bool two = (d + 4 < Tt / 64);
    __syncthreads();  // prev Qs readers done
#pragma unroll
    for (int i = 0; i < 2; i++) {
      const int rr = w * 16 + i * 8;
      ldsdma16(Qbase + (size_t)(d * 64 + rr + drr) * Dd + dsw, Qs[0] + rr * 64);
    }
    if (two) {
#pragma unroll
      for (int i = 0; i < 2; i++) {
        const int rr = w * 16 + i * 8;
        ldsdma16(Qbase + (size_t)((d + 4) * 64 + rr + drr) * Dd + dsw,
                 Qs[1] + rr * 64);
      }
    }
    __syncthreads();  // drains dma
    computeS(Qs[0], d * 64, (c < 2) && (i0 == 0));
    if (two) computeS(Qs[1], (d + 4) * 64, false);
  }

#pragma unroll
  for (int s2 = 0; s2 < 2; s2++)
#pragma unroll
    for (int r = 0; r < 4; r++) {
      float s = l[s2][r];
#pragma unroll
      for (int m = 1; m < 16; m <<= 1) s += __shfl_xor(s, m);
      if (col == 0)
        atomicAdd(&lsum[(size_t)bh * Tt + tk0 + w * 32 + s2 * 16 + quad * 4 + r], s);
    }
}

// ---------------------------------------------------------------------------
// Pass B (r9-EXACT): out[tq] = sum_{tk<=tq} exp(z)/l[tk] * v[tk].
// Block: (bh, 64 tq).  IN-REGISTER P: z = MFMA(K,Q) -> lane holds
// z[tk=jt*16+quad*4+r][tq=w*16+col]; layout == K=16 MFMA B-frag, so
// PV = mfma16(Vt-frag, cvt_pk(P)).  BATCH-2 STAGING: each barrier pair
// stages TWO tk-tiles (buffers 0,1 -- literal indices), then computes both.
// V dsw-staged (3-bit ldv4).  Heavy-first via reversed blockIdx.y.
// ---------------------------------------------------------------------------
__global__ __launch_bounds__(256) void attn_out(
    const u16* __restrict__ Qp, const u16* __restrict__ Kp,
    const u16* __restrict__ VtG, const float* __restrict__ lsum,
    u16* __restrict__ Ctx)
{
  __shared__ u16 Qs[64 * 64];
  __shared__ u16 Ks[2][64 * 64];
  __shared__ u16 Vts[2][64 * 64];   // [d][tk], dsw-staged
  __shared__ float srl[2][64];
  const int t = threadIdx.x, lane = t & 63, w = t >> 6;
  const int col = lane & 15, quad = lane >> 4;
  const int bh = blockIdx.x, b = bh >> 4, h = bh & 15;
  const int tq0 = (gridDim.y - 1 - blockIdx.y) * 64;   // heavy-first
  const u16* Qbase = Qp + (size_t)b * Tt * Dd + h * NDh;
  const u16* Kbase = Kp + (size_t)b * Tt * Dd + h * NDh;
  const u16* Vbase = VtG + (size_t)b * Dd * Tt + (size_t)h * NDh * Tt;
  const int drr = lane >> 3, dsw = ((lane & 7) ^ drr) * 8;

#pragma unroll
  for (int i = 0; i < 2; i++) {
    const int rr = w * 16 + i * 8;
    ldsdma16(Qbase + (size_t)(tq0 + rr + drr) * Dd + dsw, Qs + rr * 64);
  }
  __syncthreads();
  bf16x8 qa0 = ldfrag(Qs, w * 16 + col, quad);       // Q[tq=w*16+col][k]
  bf16x8 qa1 = ldfrag(Qs, w * 16 + col, 4 + quad);

  f32x4 o[4] = {};   // o[dn][r]: d = dn*16+quad*4+r, tq = w*16+col

  auto compute = [&](const u16* Kc, const u16* Vc, const float* rlc,
                     bool masked) {
#pragma unroll
    for (int jt = 0; jt < 4; jt++) {
      // K as A-operand: rows = tk = jt*16+col
      bf16x8 kb0 = ldfrag(Kc, jt * 16 + col, quad);
      bf16x8 kb1 = ldfrag(Kc, jt * 16 + col, 4 + quad);
      f32x4 z = {};
      z = MFMA(kb0, qa0, z);
      z = MFMA(kb1, qa1, z);
      // z[r]: tk = jt*16+quad*4+r, tq = w*16+col
      const f32x4 rl = *(const f32x4*)(rlc + jt * 16 + quad * 4);
      float p0 = exp2_hw(z[0]) * rl[0];
      float p1 = exp2_hw(z[1]) * rl[1];
      float p2 = exp2_hw(z[2]) * rl[2];
      float p3 = exp2_hw(z[3]) * rl[3];
      if (masked) {
        const int tkb = jt * 16 + quad * 4, tq = w * 16 + col;
        p0 = (tkb + 0 <= tq) ? p0 : 0.f;
        p1 = (tkb + 1 <= tq) ? p1 : 0.f;
        p2 = (tkb + 2 <= tq) ? p2 : 0.f;
        p3 = (tkb + 3 <= tq) ? p3 : 0.f;
      }
      u32 pk01 = cvtpk(p0, p1), pk23 = cvtpk(p2, p3);
      u32 pkv[2] = {pk01, pk23};
      const bf16x4 pb2 = *(const bf16x4*)pkv;   // B[k=quad*4+j][tq=col]
#pragma unroll
      for (int dn = 0; dn < 4; dn++) {
        // Vt as A-operand: A[row=d][k=tk=jt*16+quad*4+j]
        const bf16x4 va = ldv4(Vc, dn * 16 + col, jt * 16 + quad * 4);
        o[dn] = mfma16(va, pb2, o[dn]);
      }
    }
  };

  for (int tk0 = 0; tk0 <= tq0; tk0 += 128) {
    const bool two = (tk0 + 64 <= tq0);
    __syncthreads();  // prev iter LDS readers (and initial qa reads) done
#pragma unroll
    for (int i = 0; i < 2; i++) {
      const int rr = w * 16 + i * 8;
      ldsdma16(Kbase + (size_t)(tk0 + rr + drr) * Dd + dsw, Ks[0] + rr * 64);
      ldsdma16(Vbase + (size_t)(rr + drr) * Tt + tk0 + dsw, Vts[0] + rr * 64);
    }
    if (two) {
#pragma unroll
      for (int i = 0; i < 2; i++) {
        const int rr = w * 16 + i * 8;
        ldsdma16(Kbase + (size_t)(tk0 + 64 + rr + drr) * Dd + dsw,
                 Ks[1] + rr * 64);
        ldsdma16(Vbase + (size_t)(rr + drr) * Tt + tk0 + 64 + dsw,
                 Vts[1] + rr * 64);
      }
    }
    if (t < 64) {
      srl[0][t] = 1.0f / lsum[(size_t)bh * Tt + tk0 + t];
      if (two) srl[1][t] = 1.0f / lsum[(size_t)bh * Tt + tk0 + 64 + t];
    }
    __syncthreads();  // drains dma (vmcnt) + srl writes
    compute(Ks[0], Vts[0], srl[0], tk0 == tq0);
    if (two) compute(Ks[1], Vts[1], srl[1], tk0 + 64 == tq0);
  }

#pragma unroll
  for (int dn = 0; dn < 4; dn++) {
    ushort4 ov;
    ov.x = f2bf(o[dn][0]); ov.y = f2bf(o[dn][1]);
    ov.z = f2bf(o[dn][2]); ov.w = f2bf(o[dn][3]);
    *(ushort4*)(Ctx + (size_t)(b * Tt + tq0 + w * 16 + col) * Dd +
                h * NDh + dn * 16 + quad * 4) = ov;
  }
}

// ---------------------------------------------------------------------------
extern "C" void kernel_launch(void* const* d_in, const int* in_sizes, int n_in,
                              void* d_out, int out_size, void* d_ws, size_t ws_size,
                              hipStream_t stream)
{
  const float* q  = (const float*)d_in[0];
  const float* k  = (const float*)d_in[1];
  const float* v  = (const float*)d_in[2];
  const float* Wq = (const float*)d_in[3];
  const float* bq = (const float*)d_in[4];
  const float* Wk = (const float*)d_in[5];
  const float* bk = (const float*)d_in[6];
  const float* Wv = (const float*)d_in[7];
  const float* bv = (const float*)d_in[8];
  const float* Wc = (const float*)d_in[9];
  const float* bc = (const float*)d_in[10];

  u16* Wb   = (u16*)d_ws;                        // 4 * Dd*Dd bf16
  u16* Qp   = Wb + (size_t)4 * Dd * Dd;          // Mm*Dd
  u16* Kp   = Qp + (size_t)Mm * Dd;
  u16* VtG  = Kp + (size_t)Mm * Dd;              // [B, D, T] transposed
  u16* Ctx  = VtG + (size_t)Mm * Dd;
  float* lsum = (float*)(Ctx + (size_t)Mm * Dd); // Bb*Hh*Tt
  u16* Qb   = (u16*)(lsum + (size_t)Bb * Hh * Tt);  // bf16 copies of q/k/v
  u16* Kb   = Qb + (size_t)Mm * Dd;
  u16* Vb   = Ctx;  // alias: Ctx not written until attn_out, after proj reads Vb

  cvt_all<<<16384, 256, 0, stream>>>(Wq, Wk, Wv, Wc, q, k, v,
                                     Wb, Qb, Kb, Vb, (float*)d_out, lsum);
  proj_qkv<<<dim3(Mm / 64, Dd / 128, 3), 256, 0, stream>>>(
      Qb, Kb, Vb, Wb, bq, bk, bv, Qp, Kp, VtG);
  attn_stats<<<dim3(Bb * Hh, Tt / 128, 4), 256, 0, stream>>>(Qp, Kp, lsum);
  attn_out<<<dim3(Bb * Hh, Tt / 64), 256, 0, stream>>>(Qp, Kp, VtG, lsum, Ctx);
  gemm_final<<<dim3(Mm / 64, Dd / 128, 2), 256, 0, stream>>>(
      Ctx, Wb + (size_t)3 * Dd * Dd, bc, (float*)d_out);
}

// Round 12
// 245.943 us; speedup vs baseline: 1.0328x; 1.0328x over previous
//
#include <hip/hip_runtime.h>

// MHA B=2, T=2048, D=1024, H=16, nd=64. fp32 I/O, bf16 MFMA internally.
// softmax over QUERY axis (dim=-2), causal, fixed-max (|z|<~3):
//   l[tk] = sum_{tq>=tk} exp(z); out[tq] = sum_{tk<=tq} exp(z)/l[tk] * v[tk]
// Scale 1/8 * log2(e) folded into Q projection -> single v_exp_f32 per score.
// V stored pre-transposed [B, D, T] (plain; dsw-staged into LDS, 3-bit ldv4).
// Round 17 = r9 + attn_out BATCH-4 staging (single mechanism vs r9).
// r10/r11 bisect: 8-wave widening was the bug; stats-batch2 correct but
// clock-adjusted ~neutral-to-negative -> stats reverted to r9-exact.
// Batch-4 keeps the 3x-proven invariant (all DMA between two barriers,
// compute strictly after drain, literal buffer indices); drains/block
// 17 -> 9, each ~600cy drain amortized over ~1600cy compute (~20% gain).
// LDS ~73KB -> 2 blocks/CU (matches measured ~1.8 active anyway).
// GEMMs, cvt, attn_stats: r9-exact.

#define Dd 1024
#define Tt 2048
#define Bb 2
#define Hh 16
#define NDh 64
#define Mm (Bb * Tt)
#define LOG2E 1.44269504f

using u16 = unsigned short;
using u32 = unsigned int;
typedef __attribute__((ext_vector_type(8))) short bf16x8;
typedef __attribute__((ext_vector_type(4))) short bf16x4;
typedef __attribute__((ext_vector_type(4))) float f32x4;

__device__ __forceinline__ u16 f2bf(float f) {
  return (u16)((__float_as_uint(f) + 0x8000u) >> 16);
}
__device__ __forceinline__ float exp2_hw(float x) {  // single v_exp_f32
  float r; asm("v_exp_f32 %0, %1" : "=v"(r) : "v"(x)); return r;
}
__device__ __forceinline__ u32 cvtpk(float lo, float hi) {  // 2xf32 -> bf16 pair
  u32 r; asm("v_cvt_pk_bf16_f32 %0, %1, %2" : "=v"(r) : "v"(lo), "v"(hi));
  return r;
}
// async global->LDS, 16B per lane; LDS dest = base + lane*16 (wave-uniform base)
__device__ __forceinline__ void ldsdma16(const u16* g, u16* l) {
  __builtin_amdgcn_global_load_lds(
      (const __attribute__((address_space(1))) u32*)g,
      (__attribute__((address_space(3))) u32*)l, 16, 0, 0);
}
#define MFMA(a, b, c) __builtin_amdgcn_mfma_f32_16x16x32_bf16((a), (b), (c), 0, 0, 0)
__device__ __forceinline__ f32x4 mfma16(bf16x4 a, bf16x4 b, f32x4 c) {
#if __has_builtin(__builtin_amdgcn_mfma_f32_16x16x16bf16_1k)
  return __builtin_amdgcn_mfma_f32_16x16x16bf16_1k(a, b, c, 0, 0, 0);
#else
  f32x4 d;
  asm("v_mfma_f32_16x16x16_bf16 %0, %1, %2, %3"
      : "=v"(d) : "v"(a), "v"(b), "0"(c));
  return d;
#endif
}
// frag load from swizzled 64-elem-row tile (16B-granule XOR, K/Q tiles)
__device__ __forceinline__ bf16x8 ldfrag(const u16* lds, int row, int kgrp) {
  return *(const bf16x8*)(lds + row * 64 + (((kgrp) ^ (row & 7)) * 8));
}
// 4-elem (8B) load from dsw-staged tile; e0 = element offset, multiple of 4
__device__ __forceinline__ bf16x4 ldv4(const u16* lds, int row, int e0) {
  return *(const bf16x4*)(lds + row * 64 + (((e0 >> 3) ^ (row & 7)) * 8) + (e0 & 7));
}

// ---------------------------------------------------------------------------
// Convert weights (4x Dd*Dd) AND q/k/v (3x Mm*Dd) fp32 -> bf16;
// zero d_out and lsum. 16 segments of 2^18 float4 each; grid 16384x256.
// ---------------------------------------------------------------------------
__global__ __launch_bounds__(256) void cvt_all(
    const float* __restrict__ w0, const float* __restrict__ w1,
    const float* __restrict__ w2, const float* __restrict__ w3,
    const float* __restrict__ xq, const float* __restrict__ xk,
    const float* __restrict__ xv,
    u16* __restrict__ Wb, u16* __restrict__ Qb, u16* __restrict__ Kb,
    u16* __restrict__ Vb, float* __restrict__ outz, float* __restrict__ lsumz)
{
  const int vid = blockIdx.x * 256 + threadIdx.x;     // 4M vec4 units
  const int seg = vid >> 18;                          // 16 segs of 1M floats
  const size_t off = (size_t)(vid & 0x3FFFF) * 4;
  const float* s;
  u16* d;
  if (seg < 4) {                                      // weights
    s = seg == 0 ? w0 : seg == 1 ? w1 : seg == 2 ? w2 : w3;
    d = Wb + (size_t)seg * Dd * Dd;
  } else {                                            // q/k/v (4 segs each)
    const int xi = (seg - 4) >> 2;
    const size_t xo = (size_t)((seg - 4) & 3) << 20;  // sub-offset in floats
    s = (xi == 0 ? xq : xi == 1 ? xk : xv) + xo;
    d = (xi == 0 ? Qb : xi == 1 ? Kb : Vb) + xo;
  }
  float4 f = *(const float4*)(s + off);
  ushort4 o;
  o.x = f2bf(f.x); o.y = f2bf(f.y); o.z = f2bf(f.z); o.w = f2bf(f.w);
  *(ushort4*)(d + off) = o;
  if (vid < Mm * Dd / 4)                              // zero out (4M floats)
    *(float4*)(outz + (size_t)vid * 4) = make_float4(0.f, 0.f, 0.f, 0.f);
  if (vid < Bb * Hh * Tt / 4)
    *(float4*)(lsumz + (size_t)vid * 4) = make_float4(0.f, 0.f, 0.f, 0.f);
}

// ---------------------------------------------------------------------------
// GEMM body: Y[m,n] = (sum_k X[m,k]*W[n,k] + bias[n]) * oscale.  All bf16 in.
// BM=64, BN=128, BK=64, 256 thr / 4 waves (2Mx2N), wave tile 32x64 = 2x4 frags.
// Both A and B staged via global_load_lds width-16; single-buffered m97 body.
// omode 0: bf16 Y[m*Dd+n]*oscale; 1: bf16 transposed (Y[b,n,t]); 2: f32 atomic.
// Split-K: kc/knum (omode 2 only; bias added by kc==0).
// ---------------------------------------------------------------------------
__device__ __forceinline__ void gemm_body(
    const u16* __restrict__ X, const u16* __restrict__ WB,
    const float* __restrict__ bias, void* Yv, float oscale, int omode,
    int kc, int knum, u16* As, u16* Bs)
{
  const int t = threadIdx.x, lane = t & 63, w = t >> 6;
  const int col = lane & 15, quad = lane >> 4;
  const int m0 = blockIdx.x * 64, n0 = blockIdx.y * 128;
  const int wm = (w >> 1) * 32, wn = (w & 1) * 64;
  const int drr = lane >> 3, dsw = ((lane & 7) ^ drr) * 8;  // swizzled src col
  const int kbeg = (Dd / knum) * kc, kend = kbeg + Dd / knum;

  f32x4 acc[2][4] = {};

  for (int k0 = kbeg; k0 < kend; k0 += 64) {
    __syncthreads();  // previous iteration's frag readers done
#pragma unroll
    for (int i = 0; i < 2; i++) {
      const int rr = w * 16 + i * 8;
      ldsdma16(X + (size_t)(m0 + rr + drr) * Dd + k0 + dsw, As + rr * 64);
    }
#pragma unroll
    for (int i = 0; i < 4; i++) {
      const int rr = w * 32 + i * 8;
      ldsdma16(WB + (size_t)(n0 + rr + drr) * Dd + k0 + dsw, Bs + rr * 64);
    }
    __syncthreads();  // drains dma (vmcnt)
#pragma unroll
    for (int s = 0; s < 2; s++) {
      bf16x8 a[2], b[4];
#pragma unroll
      for (int i = 0; i < 2; i++)
        a[i] = ldfrag(As, wm + i * 16 + col, s * 4 + quad);
#pragma unroll
      for (int j = 0; j < 4; j++)
        b[j] = ldfrag(Bs, wn + j * 16 + col, s * 4 + quad);
#pragma unroll
      for (int i = 0; i < 2; i++)
#pragma unroll
        for (int j = 0; j < 4; j++)
          acc[i][j] = MFMA(a[i], b[j], acc[i][j]);
    }
  }

#pragma unroll
  for (int jt = 0; jt < 4; jt++) {
    const int n = n0 + wn + jt * 16 + col;
    const float bn = (omode == 2 && kc != 0) ? 0.f : bias[n];
    if (omode == 1) {
#pragma unroll
      for (int i = 0; i < 2; i++) {
        const int mg = m0 + wm + i * 16 + quad * 4;
        const int bb = mg >> 11, tl = mg & 2047;
        ushort4 o;
        o.x = f2bf(acc[i][jt][0] + bn);
        o.y = f2bf(acc[i][jt][1] + bn);
        o.z = f2bf(acc[i][jt][2] + bn);
        o.w = f2bf(acc[i][jt][3] + bn);
        *(ushort4*)((u16*)Yv + (size_t)bb * Dd * Tt + (size_t)n * Tt + tl) = o;
      }
    } else if (omode == 0) {
      u16* Y = (u16*)Yv;
#pragma unroll
      for (int i = 0; i < 2; i++)
#pragma unroll
        for (int r = 0; r < 4; r++) {
          const int m = m0 + wm + i * 16 + quad * 4 + r;
          Y[(size_t)m * Dd + n] = f2bf((acc[i][jt][r] + bn) * oscale);
        }
    } else {
      float* Y = (float*)Yv;
#pragma unroll
      for (int i = 0; i < 2; i++)
#pragma unroll
        for (int r = 0; r < 4; r++) {
          const int m = m0 + wm + i * 16 + quad * 4 + r;
          atomicAdd(&Y[(size_t)m * Dd + n], acc[i][jt][r] + bn);
        }
    }
  }
}

// Fused Q/K/V projection: blockIdx.z selects input/weight/output.
__global__ __launch_bounds__(256) void proj_qkv(
    const u16* __restrict__ Qb, const u16* __restrict__ Kb,
    const u16* __restrict__ Vb, const u16* __restrict__ Wb,
    const float* __restrict__ bq, const float* __restrict__ bk,
    const float* __restrict__ bv,
    u16* __restrict__ Qp, u16* __restrict__ Kp, u16* __restrict__ VtG)
{
  __shared__ u16 As[64 * 64];
  __shared__ u16 Bs[128 * 64];
  const int z = blockIdx.z;
  const u16* X = z == 0 ? Qb : z == 1 ? Kb : Vb;
  const u16* W = Wb + (size_t)z * Dd * Dd;
  const float* bias = z == 0 ? bq : z == 1 ? bk : bv;
  void* Y = z == 0 ? (void*)Qp : z == 1 ? (void*)Kp : (void*)VtG;
  // Q scale = 1/8 * log2(e): attn kernels then use raw exp2 (1 v_exp_f32)
  gemm_body(X, W, bias, Y, z == 0 ? 0.125f * LOG2E : 1.0f, z == 2 ? 1 : 0,
            0, 1, As, Bs);
}

__global__ __launch_bounds__(256) void gemm_final(
    const u16* __restrict__ Ctx, const u16* __restrict__ Wcb,
    const float* __restrict__ bc, float* __restrict__ out)
{
  __shared__ u16 As[64 * 64];
  __shared__ u16 Bs[128 * 64];
  gemm_body(Ctx, Wcb, bc, out, 1.0f, 2, blockIdx.z, 2, As, Bs);
}

// ---------------------------------------------------------------------------
// Pass A (r9-exact): lsum[tk] += partial sum_{tq>=tk} exp(z).
// Grid (bh, 16 tk-tiles of 128, 4 tq-chunks). Wave: 32 tk, K-frags in regs.
// ---------------------------------------------------------------------------
__global__ __launch_bounds__(256) void attn_stats(
    const u16* __restrict__ Qp, const u16* __restrict__ Kp,
    float* __restrict__ lsum)
{
  __shared__ u16 Ks[128 * 64];
  __shared__ u16 Qs[64 * 64];
  const int t = threadIdx.x, lane = t & 63, w = t >> 6;
  const int col = lane & 15, quad = lane >> 4;
  const int bh = blockIdx.x, b = bh >> 4, h = bh & 15;
  const int j = blockIdx.y, tk0 = j * 128, c = blockIdx.z;
  const u16* Kbase = Kp + (size_t)b * Tt * Dd + h * NDh;
  const u16* Qbase = Qp + (size_t)b * Tt * Dd + h * NDh;
  const int drr = lane >> 3, dsw = ((lane & 7) ^ drr) * 8;

#pragma unroll
  for (int i = 0; i < 4; i++) {
    const int rr = w * 32 + i * 8;
    ldsdma16(Kbase + (size_t)(tk0 + rr + drr) * Dd + dsw, Ks + rr * 64);
  }
  __syncthreads();
  bf16x8 ka[2][2];
#pragma unroll
  for (int s2 = 0; s2 < 2; s2++) {
    const int row = w * 32 + s2 * 16 + col;
    ka[s2][0] = ldfrag(Ks, row, quad);
    ka[s2][1] = ldfrag(Ks, row, 4 + quad);
  }

  float l[2][4] = {};

  for (int d = 2 * j + c, i0 = 0; d < Tt / 64; d += 4, i0++) {
    const bool masked = (c < 2) && (i0 == 0);
    const int tq0 = d * 64;
    __syncthreads();  // prev Qs readers done
#pragma unroll
    for (int i = 0; i < 2; i++) {
      const int rr = w * 16 + i * 8;
      ldsdma16(Qbase + (size_t)(tq0 + rr + drr) * Dd + dsw, Qs + rr * 64);
    }
    __syncthreads();
#pragma unroll
    for (int jt = 0; jt < 4; jt++) {
      bf16x8 qb0 = ldfrag(Qs, jt * 16 + col, quad);
      bf16x8 qb1 = ldfrag(Qs, jt * 16 + col, 4 + quad);
      const int tq = tq0 + jt * 16 + col;
#pragma unroll
      for (int s2 = 0; s2 < 2; s2++) {
        f32x4 z = {};
        z = MFMA(ka[s2][0], qb0, z);
        z = MFMA(ka[s2][1], qb1, z);
#pragma unroll
        for (int r = 0; r < 4; r++) {
          float e = exp2_hw(z[r]);
          if (masked) {
            const int tk = tk0 + w * 32 + s2 * 16 + quad * 4 + r;
            e = (tq >= tk) ? e : 0.f;
          }
          l[s2][r] += e;
        }
      }
    }
  }

#pragma unroll
  for (int s2 = 0; s2 < 2; s2++)
#pragma unroll
    for (int r = 0; r < 4; r++) {
      float s = l[s2][r];
#pragma unroll
      for (int m = 1; m < 16; m <<= 1) s += __shfl_xor(s, m);
      if (col == 0)
        atomicAdd(&lsum[(size_t)bh * Tt + tk0 + w * 32 + s2 * 16 + quad * 4 + r], s);
    }
}

// ---------------------------------------------------------------------------
// Pass B: out[tq] = sum_{tk<=tq} exp(z)/l[tk] * v[tk].  Block: (bh, 64 tq).
// IN-REGISTER P: z = MFMA(K,Q) -> lane holds z[tk=jt*16+quad*4+r][tq=w*16+col];
// layout == K=16 MFMA B-frag, so PV = mfma16(Vt-frag, cvt_pk(P)).
// BATCH-4 STAGING: each barrier pair stages up to FOUR tk-tiles (buffers
// 0..3, literal indices), then computes them all.  Same 3x-proven ordering:
// all DMA between two barriers, compute strictly after the drain.
// V dsw-staged (3-bit ldv4).  Heavy-first via reversed blockIdx.y.
// ---------------------------------------------------------------------------
__global__ __launch_bounds__(256) void attn_out(
    const u16* __restrict__ Qp, const u16* __restrict__ Kp,
    const u16* __restrict__ VtG, const float* __restrict__ lsum,
    u16* __restrict__ Ctx)
{
  __shared__ u16 Qs[64 * 64];
  __shared__ u16 Ks[4][64 * 64];
  __shared__ u16 Vts[4][64 * 64];   // [d][tk], dsw-staged
  __shared__ float srl[4][64];
  const int t = threadIdx.x, lane = t & 63, w = t >> 6;
  const int col = lane & 15, quad = lane >> 4;
  const int bh = blockIdx.x, b = bh >> 4, h = bh & 15;
  const int tq0 = (gridDim.y - 1 - blockIdx.y) * 64;   // heavy-first
  const u16* Qbase = Qp + (size_t)b * Tt * Dd + h * NDh;
  const u16* Kbase = Kp + (size_t)b * Tt * Dd + h * NDh;
  const u16* Vbase = VtG + (size_t)b * Dd * Tt + (size_t)h * NDh * Tt;
  const int drr = lane >> 3, dsw = ((lane & 7) ^ drr) * 8;

#pragma unroll
  for (int i = 0; i < 2; i++) {
    const int rr = w * 16 + i * 8;
    ldsdma16(Qbase + (size_t)(tq0 + rr + drr) * Dd + dsw, Qs + rr * 64);
  }
  __syncthreads();
  bf16x8 qa0 = ldfrag(Qs, w * 16 + col, quad);       // Q[tq=w*16+col][k]
  bf16x8 qa1 = ldfrag(Qs, w * 16 + col, 4 + quad);

  f32x4 o[4] = {};   // o[dn][r]: d = dn*16+quad*4+r, tq = w*16+col

  auto compute = [&](const u16* Kc, const u16* Vc, const float* rlc,
                     bool masked) {
#pragma unroll
    for (int jt = 0; jt < 4; jt++) {
      // K as A-operand: rows = tk = jt*16+col
      bf16x8 kb0 = ldfrag(Kc, jt * 16 + col, quad);
      bf16x8 kb1 = ldfrag(Kc, jt * 16 + col, 4 + quad);
      f32x4 z = {};
      z = MFMA(kb0, qa0, z);
      z = MFMA(kb1, qa1, z);
      // z[r]: tk = jt*16+quad*4+r, tq = w*16+col
      const f32x4 rl = *(const f32x4*)(rlc + jt * 16 + quad * 4);
      float p0 = exp2_hw(z[0]) * rl[0];
      float p1 = exp2_hw(z[1]) * rl[1];
      float p2 = exp2_hw(z[2]) * rl[2];
      float p3 = exp2_hw(z[3]) * rl[3];
      if (masked) {
        const int tkb = jt * 16 + quad * 4, tq = w * 16 + col;
        p0 = (tkb + 0 <= tq) ? p0 : 0.f;
        p1 = (tkb + 1 <= tq) ? p1 : 0.f;
        p2 = (tkb + 2 <= tq) ? p2 : 0.f;
        p3 = (tkb + 3 <= tq) ? p3 : 0.f;
      }
      u32 pk01 = cvtpk(p0, p1), pk23 = cvtpk(p2, p3);
      u32 pkv[2] = {pk01, pk23};
      const bf16x4 pb2 = *(const bf16x4*)pkv;   // B[k=quad*4+j][tq=col]
#pragma unroll
      for (int dn = 0; dn < 4; dn++) {
        // Vt as A-operand: A[row=d][k=tk=jt*16+quad*4+j]
        const bf16x4 va = ldv4(Vc, dn * 16 + col, jt * 16 + quad * 4);
        o[dn] = mfma16(va, pb2, o[dn]);
      }
    }
  };

  for (int tk0 = 0; tk0 <= tq0; tk0 += 256) {
    const bool t1 = (tk0 + 64 <= tq0);
    const bool t2 = (tk0 + 128 <= tq0);
    const bool t3 = (tk0 + 192 <= tq0);
    __syncthreads();  // prev iter LDS readers (and initial qa reads) done
#pragma unroll
    for (int i = 0; i < 2; i++) {
      const int rr = w * 16 + i * 8;
      ldsdma16(Kbase + (size_t)(tk0 + rr + drr) * Dd + dsw, Ks[0] + rr * 64);
      ldsdma16(Vbase + (size_t)(rr + drr) * Tt + tk0 + dsw, Vts[0] + rr * 64);
    }
    if (t1) {
#pragma unroll
      for (int i = 0; i < 2; i++) {
        const int rr = w * 16 + i * 8;
        ldsdma16(Kbase + (size_t)(tk0 + 64 + rr + drr) * Dd + dsw,
                 Ks[1] + rr * 64);
        ldsdma16(Vbase + (size_t)(rr + drr) * Tt + tk0 + 64 + dsw,
                 Vts[1] + rr * 64);
      }
    }
    if (t2) {
#pragma unroll
      for (int i = 0; i < 2; i++) {
        const int rr = w * 16 + i * 8;
        ldsdma16(Kbase + (size_t)(tk0 + 128 + rr + drr) * Dd + dsw,
                 Ks[2] + rr * 64);
        ldsdma16(Vbase + (size_t)(rr + drr) * Tt + tk0 + 128 + dsw,
                 Vts[2] + rr * 64);
      }
    }
    if (t3) {
#pragma unroll
      for (int i = 0; i < 2; i++) {
        const int rr = w * 16 + i * 8;
        ldsdma16(Kbase + (size_t)(tk0 + 192 + rr + drr) * Dd + dsw,
                 Ks[3] + rr * 64);
        ldsdma16(Vbase + (size_t)(rr + drr) * Tt + tk0 + 192 + dsw,
                 Vts[3] + rr * 64);
      }
    }
    if (t < 64) {
      srl[0][t] = 1.0f / lsum[(size_t)bh * Tt + tk0 + t];
      if (t1) srl[1][t] = 1.0f / lsum[(size_t)bh * Tt + tk0 + 64 + t];
      if (t2) srl[2][t] = 1.0f / lsum[(size_t)bh * Tt + tk0 + 128 + t];
      if (t3) srl[3][t] = 1.0f / lsum[(size_t)bh * Tt + tk0 + 192 + t];
    }
    __syncthreads();  // drains dma (vmcnt) + srl writes
    compute(Ks[0], Vts[0], srl[0], tk0 == tq0);
    if (t1) compute(Ks[1], Vts[1], srl[1], tk0 + 64 == tq0);
    if (t2) compute(Ks[2], Vts[2], srl[2], tk0 + 128 == tq0);
    if (t3) compute(Ks[3], Vts[3], srl[3], tk0 + 192 == tq0);
  }

#pragma unroll
  for (int dn = 0; dn < 4; dn++) {
    ushort4 ov;
    ov.x = f2bf(o[dn][0]); ov.y = f2bf(o[dn][1]);
    ov.z = f2bf(o[dn][2]); ov.w = f2bf(o[dn][3]);
    *(ushort4*)(Ctx + (size_t)(b * Tt + tq0 + w * 16 + col) * Dd +
                h * NDh + dn * 16 + quad * 4) = ov;
  }
}

// ---------------------------------------------------------------------------
extern "C" void kernel_launch(void* const* d_in, const int* in_sizes, int n_in,
                              void* d_out, int out_size, void* d_ws, size_t ws_size,
                              hipStream_t stream)
{
  const float* q  = (const float*)d_in[0];
  const float* k  = (const float*)d_in[1];
  const float* v  = (const float*)d_in[2];
  const float* Wq = (const float*)d_in[3];
  const float* bq = (const float*)d_in[4];
  const float* Wk = (const float*)d_in[5];
  const float* bk = (const float*)d_in[6];
  const float* Wv = (const float*)d_in[7];
  const float* bv = (const float*)d_in[8];
  const float* Wc = (const float*)d_in[9];
  const float* bc = (const float*)d_in[10];

  u16* Wb   = (u16*)d_ws;                        // 4 * Dd*Dd bf16
  u16* Qp   = Wb + (size_t)4 * Dd * Dd;          // Mm*Dd
  u16* Kp   = Qp + (size_t)Mm * Dd;
  u16* VtG  = Kp + (size_t)Mm * Dd;              // [B, D, T] transposed
  u16* Ctx  = VtG + (size_t)Mm * Dd;
  float* lsum = (float*)(Ctx + (size_t)Mm * Dd); // Bb*Hh*Tt
  u16* Qb   = (u16*)(lsum + (size_t)Bb * Hh * Tt);  // bf16 copies of q/k/v
  u16* Kb   = Qb + (size_t)Mm * Dd;
  u16* Vb   = Ctx;  // alias: Ctx not written until attn_out, after proj reads Vb

  cvt_all<<<16384, 256, 0, stream>>>(Wq, Wk, Wv, Wc, q, k, v,
                                     Wb, Qb, Kb, Vb, (float*)d_out, lsum);
  proj_qkv<<<dim3(Mm / 64, Dd / 128, 3), 256, 0, stream>>>(
      Qb, Kb, Vb, Wb, bq, bk, bv, Qp, Kp, VtG);
  attn_stats<<<dim3(Bb * Hh, Tt / 128, 4), 256, 0, stream>>>(Qp, Kp, lsum);
  attn_out<<<dim3(Bb * Hh, Tt / 64), 256, 0, stream>>>(Qp, Kp, VtG, lsum, Ctx);
  gemm_final<<<dim3(Mm / 64, Dd / 128, 2), 256, 0, stream>>>(
      Ctx, Wb + (size_t)3 * Dd * Dd, bc, (float*)d_out);
}